// Round 5
// baseline (219.623 us; speedup 1.0000x reference)
//
#include <hip/hip_runtime.h>

#define Bdim 32
#define Sdim 512
#define Hdim 1024
#define NEG 10
#define ROWS (Bdim * (Sdim - 1))   // 16352
#define WAVES_PER_BLOCK 4          // 256 threads, 4 rows per block

// min 2 waves/EU -> VGPR cap 256/wave; we want ~200 VGPR to keep all 10
// gathered rows in flight simultaneously (ILP latency hiding).
__global__ __launch_bounds__(256, 2) void infonce_ilp_kernel(
    const float* __restrict__ enc,     // (B, S, H)
    const float* __restrict__ emb,     // (B, S, H)
    const int*   __restrict__ negidx,  // (B, S-1, NEG)
    const float* __restrict__ temp,    // scalar
    float* __restrict__ out)           // scalar (pre-zeroed)
{
    const int tid  = threadIdx.x;
    const int wave = tid >> 6;
    const int lane = tid & 63;
    const int row  = blockIdx.x * WAVES_PER_BLOCK + wave;   // 0..ROWS-1
    const int b    = row / (Sdim - 1);
    const int s    = row % (Sdim - 1);

    const float4* pred = (const float4*)(enc + (size_t)(b * Sdim + s) * Hdim);
    const float4* pos  = (const float4*)(emb + (size_t)(b * Sdim + s + 1) * Hdim);

    const int* ni = negidx + (size_t)row * NEG;
    int idx[NEG];
#pragma unroll
    for (int n = 0; n < NEG; ++n) {
        int v = ni[n];
        idx[n] = v + ((v >= b * Sdim) ? Sdim : 0);
    }

    // Issue ALL loads up front: pred(4) + pos(4) + 10x4 gathers = 48 float4
    // loads in flight per lane. This is the whole point of this revision.
    float4 p[4], q[4];
#pragma unroll
    for (int j = 0; j < 4; ++j) p[j] = pred[lane + 64 * j];
#pragma unroll
    for (int j = 0; j < 4; ++j) q[j] = pos[lane + 64 * j];

    float4 nv[NEG][4];
#pragma unroll
    for (int n = 0; n < NEG; ++n) {
        const float4* neg = (const float4*)(emb + (size_t)idx[n] * Hdim);
#pragma unroll
        for (int j = 0; j < 4; ++j) nv[n][j] = neg[lane + 64 * j];
    }

    // acc[0]=pos dot, acc[1]=|p|^2, acc[2]=|q|^2, acc[3..12]=neg dots
    float acc[13];
#pragma unroll
    for (int k = 0; k < 13; ++k) acc[k] = 0.0f;

#pragma unroll
    for (int j = 0; j < 4; ++j) {
        acc[0] += p[j].x * q[j].x + p[j].y * q[j].y + p[j].z * q[j].z + p[j].w * q[j].w;
        acc[1] += p[j].x * p[j].x + p[j].y * p[j].y + p[j].z * p[j].z + p[j].w * p[j].w;
        acc[2] += q[j].x * q[j].x + q[j].y * q[j].y + q[j].z * q[j].z + q[j].w * q[j].w;
    }

#pragma unroll
    for (int n = 0; n < NEG; ++n) {
        float d = 0.0f;
#pragma unroll
        for (int j = 0; j < 4; ++j)
            d += p[j].x * nv[n][j].x + p[j].y * nv[n][j].y
               + p[j].z * nv[n][j].z + p[j].w * nv[n][j].w;
        acc[3 + n] = d;
    }

    // wave64 butterfly reduction
#pragma unroll
    for (int k = 0; k < 13; ++k) {
        float v = acc[k];
#pragma unroll
        for (int off = 1; off < 64; off <<= 1)
            v += __shfl_xor(v, off, 64);
        acc[k] = v;
    }

    __shared__ float wloss[WAVES_PER_BLOCK];
    if (lane == 0) {
        const float t    = *temp;
        const float invt = 1.0f / t;
        const float pn = fmaxf(sqrtf(acc[1]), 1e-8f);
        const float qn = fmaxf(sqrtf(acc[2]), 1e-8f);
        const float pos_score = acc[0] / (pn * qn) * invt;

        float m = pos_score;
        float negs[NEG];
#pragma unroll
        for (int n = 0; n < NEG; ++n) {
            negs[n] = acc[3 + n] * invt;
            m = fmaxf(m, negs[n]);
        }
        float sum = expf(pos_score - m);
#pragma unroll
        for (int n = 0; n < NEG; ++n) sum += expf(negs[n] - m);
        const float lse = m + logf(sum);

        wloss[wave] = (lse - pos_score) * (1.0f / (float)ROWS);
    }
    __syncthreads();

    if (tid == 0) {
        float sum = 0.0f;
#pragma unroll
        for (int w = 0; w < WAVES_PER_BLOCK; ++w) sum += wloss[w];
        atomicAdd(out, sum);
    }
}

extern "C" void kernel_launch(void* const* d_in, const int* in_sizes, int n_in,
                              void* d_out, int out_size, void* d_ws, size_t ws_size,
                              hipStream_t stream) {
    const float* enc    = (const float*)d_in[0];
    const float* emb    = (const float*)d_in[1];
    const int*   negidx = (const int*)d_in[2];
    const float* temp   = (const float*)d_in[3];
    float* out = (float*)d_out;

    hipMemsetAsync(out, 0, sizeof(float) * out_size, stream);
    infonce_ilp_kernel<<<ROWS / WAVES_PER_BLOCK, 256, 0, stream>>>(enc, emb, negidx, temp, out);
}

// Round 6
// 187.533 us; speedup vs baseline: 1.1711x; 1.1711x over previous
//
#include <hip/hip_runtime.h>

#define Bdim 32
#define Sdim 512
#define Hdim 1024
#define NEG 10
#define ROWS (Bdim * (Sdim - 1))   // 16352
#define WAVES_PER_BLOCK 8          // 512 threads, 8 rows per block
#define EMB_ELEMS (Bdim * Sdim * Hdim)   // 16,777,216

static __device__ __forceinline__ unsigned short f2bf(float f) {
    union { float f; unsigned int u; } v; v.f = f;
    unsigned int r = v.u + 0x7FFFu + ((v.u >> 16) & 1u);   // RNE
    return (unsigned short)(r >> 16);
}
static __device__ __forceinline__ float bf2f(unsigned int lo16) {
    union { unsigned int u; float f; } v; v.u = lo16 << 16;
    return v.f;
}

// Pass 1: fp32 emb -> bf16 copy in workspace. 8 floats/thread, exact grid.
__global__ __launch_bounds__(256) void emb_to_bf16_kernel(
    const float* __restrict__ emb, unsigned short* __restrict__ out)
{
    const int i = blockIdx.x * 256 + threadIdx.x;   // 8-float chunk id
    const float4* src = (const float4*)emb;
    float4 a = src[2 * i];
    float4 b = src[2 * i + 1];
    uint4 o;
    o.x = (unsigned)f2bf(a.x) | ((unsigned)f2bf(a.y) << 16);
    o.y = (unsigned)f2bf(a.z) | ((unsigned)f2bf(a.w) << 16);
    o.z = (unsigned)f2bf(b.x) | ((unsigned)f2bf(b.y) << 16);
    o.w = (unsigned)f2bf(b.z) | ((unsigned)f2bf(b.w) << 16);
    ((uint4*)out)[i] = o;
}

// Pass 2: one wave per (b,s) row. pred fp32; pos + negatives from bf16 copy.
__global__ __launch_bounds__(512) void infonce_bf16_kernel(
    const float* __restrict__ enc,
    const unsigned short* __restrict__ embh,   // bf16 copy (B*S*H)
    const int*   __restrict__ negidx,
    const float* __restrict__ temp,
    float* __restrict__ out)
{
    const int tid  = threadIdx.x;
    const int wave = tid >> 6;
    const int lane = tid & 63;
    const int row  = blockIdx.x * WAVES_PER_BLOCK + wave;
    const int b    = row / (Sdim - 1);
    const int s    = row % (Sdim - 1);

    const float4* pred = (const float4*)(enc + (size_t)(b * Sdim + s) * Hdim);
    const uint2*  pos  = (const uint2*)(embh + (size_t)(b * Sdim + s + 1) * Hdim);

    const int* ni = negidx + (size_t)row * NEG;
    int idx[NEG];
#pragma unroll
    for (int n = 0; n < NEG; ++n) {
        int v = ni[n];
        idx[n] = v + ((v >= b * Sdim) ? Sdim : 0);
    }

    // lane owns elems 4*(lane+64j)+0..3, j=0..3 (fp32 float4 / bf16 uint2 match)
    float4 p[4];
#pragma unroll
    for (int j = 0; j < 4; ++j) p[j] = pred[lane + 64 * j];

    float acc[13];
#pragma unroll
    for (int k = 0; k < 13; ++k) acc[k] = 0.0f;

#pragma unroll
    for (int j = 0; j < 4; ++j) {
        uint2 g = pos[lane + 64 * j];
        float q0 = bf2f(g.x & 0xFFFFu), q1 = bf2f(g.x >> 16);
        float q2 = bf2f(g.y & 0xFFFFu), q3 = bf2f(g.y >> 16);
        acc[0] += p[j].x * q0 + p[j].y * q1 + p[j].z * q2 + p[j].w * q3;
        acc[1] += p[j].x * p[j].x + p[j].y * p[j].y + p[j].z * p[j].z + p[j].w * p[j].w;
        acc[2] += q0 * q0 + q1 * q1 + q2 * q2 + q3 * q3;
    }

#pragma unroll
    for (int n = 0; n < NEG; ++n) {
        const uint2* nrow = (const uint2*)(embh + (size_t)idx[n] * Hdim);
        float d = 0.0f;
#pragma unroll
        for (int j = 0; j < 4; ++j) {
            uint2 g = nrow[lane + 64 * j];
            d += p[j].x * bf2f(g.x & 0xFFFFu) + p[j].y * bf2f(g.x >> 16)
               + p[j].z * bf2f(g.y & 0xFFFFu) + p[j].w * bf2f(g.y >> 16);
        }
        acc[3 + n] = d;
    }

#pragma unroll
    for (int k = 0; k < 13; ++k) {
        float v = acc[k];
#pragma unroll
        for (int off = 1; off < 64; off <<= 1)
            v += __shfl_xor(v, off, 64);
        acc[k] = v;
    }

    __shared__ float wloss[WAVES_PER_BLOCK];
    if (lane == 0) {
        const float invt = 1.0f / *temp;
        const float pn = fmaxf(sqrtf(acc[1]), 1e-8f);
        const float qn = fmaxf(sqrtf(acc[2]), 1e-8f);
        const float pos_score = acc[0] / (pn * qn) * invt;

        float m = pos_score;
        float negs[NEG];
#pragma unroll
        for (int n = 0; n < NEG; ++n) {
            negs[n] = acc[3 + n] * invt;
            m = fmaxf(m, negs[n]);
        }
        float sum = expf(pos_score - m);
#pragma unroll
        for (int n = 0; n < NEG; ++n) sum += expf(negs[n] - m);
        const float lse = m + logf(sum);

        wloss[wave] = (lse - pos_score) * (1.0f / (float)ROWS);
    }
    __syncthreads();

    if (tid == 0) {
        float sum = 0.0f;
#pragma unroll
        for (int w = 0; w < WAVES_PER_BLOCK; ++w) sum += wloss[w];
        atomicAdd(out, sum);
    }
}

// fp32 fallback (ws too small) — round-4 kernel.
__global__ __launch_bounds__(512) void infonce_wave_kernel(
    const float* __restrict__ enc, const float* __restrict__ emb,
    const int* __restrict__ negidx, const float* __restrict__ temp,
    float* __restrict__ out)
{
    const int tid  = threadIdx.x;
    const int wave = tid >> 6;
    const int lane = tid & 63;
    const int row  = blockIdx.x * WAVES_PER_BLOCK + wave;
    const int b    = row / (Sdim - 1);
    const int s    = row % (Sdim - 1);

    const float4* pred = (const float4*)(enc + (size_t)(b * Sdim + s) * Hdim);
    const float4* pos  = (const float4*)(emb + (size_t)(b * Sdim + s + 1) * Hdim);

    const int* ni = negidx + (size_t)row * NEG;
    int idx[NEG];
#pragma unroll
    for (int n = 0; n < NEG; ++n) {
        int v = ni[n];
        idx[n] = v + ((v >= b * Sdim) ? Sdim : 0);
    }

    float4 p[4], q[4];
#pragma unroll
    for (int j = 0; j < 4; ++j) p[j] = pred[lane + 64 * j];
#pragma unroll
    for (int j = 0; j < 4; ++j) q[j] = pos[lane + 64 * j];

    float acc[13];
#pragma unroll
    for (int k = 0; k < 13; ++k) acc[k] = 0.0f;
#pragma unroll
    for (int j = 0; j < 4; ++j) {
        acc[0] += p[j].x * q[j].x + p[j].y * q[j].y + p[j].z * q[j].z + p[j].w * q[j].w;
        acc[1] += p[j].x * p[j].x + p[j].y * p[j].y + p[j].z * p[j].z + p[j].w * p[j].w;
        acc[2] += q[j].x * q[j].x + q[j].y * q[j].y + q[j].z * q[j].z + q[j].w * q[j].w;
    }
#pragma unroll
    for (int n = 0; n < NEG; ++n) {
        const float4* neg = (const float4*)(emb + (size_t)idx[n] * Hdim);
        float d = 0.0f;
#pragma unroll
        for (int j = 0; j < 4; ++j) {
            float4 v = neg[lane + 64 * j];
            d += p[j].x * v.x + p[j].y * v.y + p[j].z * v.z + p[j].w * v.w;
        }
        acc[3 + n] = d;
    }
#pragma unroll
    for (int k = 0; k < 13; ++k) {
        float v = acc[k];
#pragma unroll
        for (int off = 1; off < 64; off <<= 1)
            v += __shfl_xor(v, off, 64);
        acc[k] = v;
    }
    __shared__ float wloss[WAVES_PER_BLOCK];
    if (lane == 0) {
        const float invt = 1.0f / *temp;
        const float pn = fmaxf(sqrtf(acc[1]), 1e-8f);
        const float qn = fmaxf(sqrtf(acc[2]), 1e-8f);
        const float pos_score = acc[0] / (pn * qn) * invt;
        float m = pos_score;
        float negs[NEG];
#pragma unroll
        for (int n = 0; n < NEG; ++n) {
            negs[n] = acc[3 + n] * invt;
            m = fmaxf(m, negs[n]);
        }
        float sum = expf(pos_score - m);
#pragma unroll
        for (int n = 0; n < NEG; ++n) sum += expf(negs[n] - m);
        wloss[wave] = (m + logf(sum) - pos_score) * (1.0f / (float)ROWS);
    }
    __syncthreads();
    if (tid == 0) {
        float sum = 0.0f;
#pragma unroll
        for (int w = 0; w < WAVES_PER_BLOCK; ++w) sum += wloss[w];
        atomicAdd(out, sum);
    }
}

extern "C" void kernel_launch(void* const* d_in, const int* in_sizes, int n_in,
                              void* d_out, int out_size, void* d_ws, size_t ws_size,
                              hipStream_t stream) {
    const float* enc    = (const float*)d_in[0];
    const float* emb    = (const float*)d_in[1];
    const int*   negidx = (const int*)d_in[2];
    const float* temp   = (const float*)d_in[3];
    float* out = (float*)d_out;

    hipMemsetAsync(out, 0, sizeof(float) * out_size, stream);

    if (ws_size >= (size_t)EMB_ELEMS * 2) {
        unsigned short* embh = (unsigned short*)d_ws;
        emb_to_bf16_kernel<<<EMB_ELEMS / 8 / 256, 256, 0, stream>>>(emb, embh);
        infonce_bf16_kernel<<<ROWS / WAVES_PER_BLOCK, 512, 0, stream>>>(
            enc, embh, negidx, temp, out);
    } else {
        infonce_wave_kernel<<<ROWS / WAVES_PER_BLOCK, 512, 0, stream>>>(
            enc, emb, negidx, temp, out);
    }
}

// Round 11
// 174.623 us; speedup vs baseline: 1.2577x; 1.0739x over previous
//
#include <hip/hip_runtime.h>

#define Bdim 32
#define Sdim 512
#define Hdim 1024
#define NEG 10
#define ROWS (Bdim * (Sdim - 1))   // 16352
#define WAVES_PER_BLOCK 8          // 512 threads, 8 rows per block
#define EMB_ELEMS (Bdim * Sdim * Hdim)   // 16,777,216

typedef float f32x2 __attribute__((ext_vector_type(2)));

// decode 4 packed fp8 (one dword) -> 4 floats via HW converter
static __device__ __forceinline__ void dec4(unsigned int w, float q[4]) {
    f32x2 lo = __builtin_amdgcn_cvt_pk_f32_fp8(w, false);
    f32x2 hi = __builtin_amdgcn_cvt_pk_f32_fp8(w, true);
    q[0] = lo.x; q[1] = lo.y; q[2] = hi.x; q[3] = hi.y;
}

// Pass 1: fp32 emb -> fp8 e4m3 copy in workspace. 8 floats/thread.
__global__ __launch_bounds__(256) void emb_to_fp8_kernel(
    const float* __restrict__ emb, unsigned int* __restrict__ out)
{
    const int i = blockIdx.x * 256 + threadIdx.x;   // 8-float chunk id
    const float4* src = (const float4*)emb;
    float4 a = src[2 * i];
    float4 b = src[2 * i + 1];
    unsigned int w0 = 0, w1 = 0;
    w0 = __builtin_amdgcn_cvt_pk_fp8_f32(a.x, a.y, w0, false);
    w0 = __builtin_amdgcn_cvt_pk_fp8_f32(a.z, a.w, w0, true);
    w1 = __builtin_amdgcn_cvt_pk_fp8_f32(b.x, b.y, w1, false);
    w1 = __builtin_amdgcn_cvt_pk_fp8_f32(b.z, b.w, w1, true);
    uint2 o; o.x = w0; o.y = w1;
    ((uint2*)out)[i] = o;
}

// Pass 2: one wave per (b,s) row. pred fp32; pos + negatives from fp8 copy.
// Lane owns 16 CONTIGUOUS elements [16*lane, 16*lane+16): fp8 row slice is one
// dwordx4, pred slice is 4x float4 at float4-index 4*lane+k.
__global__ __launch_bounds__(512) void infonce_fp8_kernel(
    const float* __restrict__ enc,
    const unsigned int* __restrict__ emb8,   // fp8 copy (B*S*H bytes /4)
    const int*   __restrict__ negidx,
    const float* __restrict__ temp,
    float* __restrict__ out)
{
    const int tid  = threadIdx.x;
    const int wave = tid >> 6;
    const int lane = tid & 63;
    const int row  = blockIdx.x * WAVES_PER_BLOCK + wave;
    const int b    = row / (Sdim - 1);
    const int s    = row % (Sdim - 1);

    const float4* pred = (const float4*)(enc + (size_t)(b * Sdim + s) * Hdim);
    const uint4*  pos  = (const uint4*)(emb8 + (size_t)(b * Sdim + s + 1) * (Hdim / 4));

    const int* ni = negidx + (size_t)row * NEG;
    int idx[NEG];
#pragma unroll
    for (int n = 0; n < NEG; ++n) {
        int v = ni[n];
        idx[n] = v + ((v >= b * Sdim) ? Sdim : 0);
    }

    float4 p[4];
#pragma unroll
    for (int k = 0; k < 4; ++k) p[k] = pred[4 * lane + k];

    float acc[13];
#pragma unroll
    for (int k = 0; k < 13; ++k) acc[k] = 0.0f;

    // positive: dot, |p|^2, |q|^2
    {
        uint4 g = pos[lane];
        unsigned int w[4] = {g.x, g.y, g.z, g.w};
#pragma unroll
        for (int k = 0; k < 4; ++k) {
            float q[4]; dec4(w[k], q);
            acc[0] += p[k].x * q[0] + p[k].y * q[1] + p[k].z * q[2] + p[k].w * q[3];
            acc[1] += p[k].x * p[k].x + p[k].y * p[k].y + p[k].z * p[k].z + p[k].w * p[k].w;
            acc[2] += q[0] * q[0] + q[1] * q[1] + q[2] * q[2] + q[3] * q[3];
        }
    }

#pragma unroll
    for (int n = 0; n < NEG; ++n) {
        const uint4* nrow = (const uint4*)(emb8 + (size_t)idx[n] * (Hdim / 4));
        uint4 g = nrow[lane];
        unsigned int w[4] = {g.x, g.y, g.z, g.w};
        float d = 0.0f;
#pragma unroll
        for (int k = 0; k < 4; ++k) {
            float q[4]; dec4(w[k], q);
            d += p[k].x * q[0] + p[k].y * q[1] + p[k].z * q[2] + p[k].w * q[3];
        }
        acc[3 + n] = d;
    }

#pragma unroll
    for (int k = 0; k < 13; ++k) {
        float v = acc[k];
#pragma unroll
        for (int off = 1; off < 64; off <<= 1)
            v += __shfl_xor(v, off, 64);
        acc[k] = v;
    }

    __shared__ float wloss[WAVES_PER_BLOCK];
    if (lane == 0) {
        const float invt = 1.0f / *temp;
        const float pn = fmaxf(sqrtf(acc[1]), 1e-8f);
        const float qn = fmaxf(sqrtf(acc[2]), 1e-8f);
        const float pos_score = acc[0] / (pn * qn) * invt;

        float m = pos_score;
        float negs[NEG];
#pragma unroll
        for (int n = 0; n < NEG; ++n) {
            negs[n] = acc[3 + n] * invt;
            m = fmaxf(m, negs[n]);
        }
        float sum = expf(pos_score - m);
#pragma unroll
        for (int n = 0; n < NEG; ++n) sum += expf(negs[n] - m);
        const float lse = m + logf(sum);

        wloss[wave] = (lse - pos_score) * (1.0f / (float)ROWS);
    }
    __syncthreads();

    if (tid == 0) {
        float sum = 0.0f;
#pragma unroll
        for (int w = 0; w < WAVES_PER_BLOCK; ++w) sum += wloss[w];
        atomicAdd(out, sum);
    }
}

// fp32 fallback (ws too small) — round-4 kernel.
__global__ __launch_bounds__(512) void infonce_wave_kernel(
    const float* __restrict__ enc, const float* __restrict__ emb,
    const int* __restrict__ negidx, const float* __restrict__ temp,
    float* __restrict__ out)
{
    const int tid  = threadIdx.x;
    const int wave = tid >> 6;
    const int lane = tid & 63;
    const int row  = blockIdx.x * WAVES_PER_BLOCK + wave;
    const int b    = row / (Sdim - 1);
    const int s    = row % (Sdim - 1);

    const float4* pred = (const float4*)(enc + (size_t)(b * Sdim + s) * Hdim);
    const float4* pos  = (const float4*)(emb + (size_t)(b * Sdim + s + 1) * Hdim);

    const int* ni = negidx + (size_t)row * NEG;
    int idx[NEG];
#pragma unroll
    for (int n = 0; n < NEG; ++n) {
        int v = ni[n];
        idx[n] = v + ((v >= b * Sdim) ? Sdim : 0);
    }

    float4 p[4], q[4];
#pragma unroll
    for (int j = 0; j < 4; ++j) p[j] = pred[lane + 64 * j];
#pragma unroll
    for (int j = 0; j < 4; ++j) q[j] = pos[lane + 64 * j];

    float acc[13];
#pragma unroll
    for (int k = 0; k < 13; ++k) acc[k] = 0.0f;
#pragma unroll
    for (int j = 0; j < 4; ++j) {
        acc[0] += p[j].x * q[j].x + p[j].y * q[j].y + p[j].z * q[j].z + p[j].w * q[j].w;
        acc[1] += p[j].x * p[j].x + p[j].y * p[j].y + p[j].z * p[j].z + p[j].w * p[j].w;
        acc[2] += q[j].x * q[j].x + q[j].y * q[j].y + q[j].z * q[j].z + q[j].w * q[j].w;
    }
#pragma unroll
    for (int n = 0; n < NEG; ++n) {
        const float4* neg = (const float4*)(emb + (size_t)idx[n] * Hdim);
        float d = 0.0f;
#pragma unroll
        for (int j = 0; j < 4; ++j) {
            float4 v = neg[lane + 64 * j];
            d += p[j].x * v.x + p[j].y * v.y + p[j].z * v.z + p[j].w * v.w;
        }
        acc[3 + n] = d;
    }
#pragma unroll
    for (int k = 0; k < 13; ++k) {
        float v = acc[k];
#pragma unroll
        for (int off = 1; off < 64; off <<= 1)
            v += __shfl_xor(v, off, 64);
        acc[k] = v;
    }
    __shared__ float wloss[WAVES_PER_BLOCK];
    if (lane == 0) {
        const float invt = 1.0f / *temp;
        const float pn = fmaxf(sqrtf(acc[1]), 1e-8f);
        const float qn = fmaxf(sqrtf(acc[2]), 1e-8f);
        const float pos_score = acc[0] / (pn * qn) * invt;
        float m = pos_score;
        float negs[NEG];
#pragma unroll
        for (int n = 0; n < NEG; ++n) {
            negs[n] = acc[3 + n] * invt;
            m = fmaxf(m, negs[n]);
        }
        float sum = expf(pos_score - m);
#pragma unroll
        for (int n = 0; n < NEG; ++n) sum += expf(negs[n] - m);
        wloss[wave] = (m + logf(sum) - pos_score) * (1.0f / (float)ROWS);
    }
    __syncthreads();
    if (tid == 0) {
        float sum = 0.0f;
#pragma unroll
        for (int w = 0; w < WAVES_PER_BLOCK; ++w) sum += wloss[w];
        atomicAdd(out, sum);
    }
}

extern "C" void kernel_launch(void* const* d_in, const int* in_sizes, int n_in,
                              void* d_out, int out_size, void* d_ws, size_t ws_size,
                              hipStream_t stream) {
    const float* enc    = (const float*)d_in[0];
    const float* emb    = (const float*)d_in[1];
    const int*   negidx = (const int*)d_in[2];
    const float* temp   = (const float*)d_in[3];
    float* out = (float*)d_out;

    hipMemsetAsync(out, 0, sizeof(float) * out_size, stream);

    if (ws_size >= (size_t)EMB_ELEMS) {
        unsigned int* emb8 = (unsigned int*)d_ws;
        emb_to_fp8_kernel<<<EMB_ELEMS / 8 / 256, 256, 0, stream>>>(emb, emb8);
        infonce_fp8_kernel<<<ROWS / WAVES_PER_BLOCK, 512, 0, stream>>>(
            enc, emb8, negidx, temp, out);
    } else {
        infonce_wave_kernel<<<ROWS / WAVES_PER_BLOCK, 512, 0, stream>>>(
            enc, emb, negidx, temp, out);
    }
}